// Round 5
// baseline (133.116 us; speedup 1.0000x reference)
//
#include <hip/hip_runtime.h>

#define NTOK 2048
#define IN_DIM 1024
#define OUT_DIM 512
#define RNK 32
#define TG_N 32
#define TGK_N 128
#define AWCOLS 4096
#define KD 4224          // 4096 affine_w cols + 128 bias-indicator cols
#define NKT 66           // KD / 64
#define SCALE_F 0.17677669529663687f
#define W2T_BLOCKS 2112  // (KD/32) * (OUT_DIM/32)

typedef __attribute__((ext_vector_type(8))) short short8;
typedef __attribute__((ext_vector_type(4))) float float4v;

__device__ __forceinline__ unsigned short f2bf(float f) {
  union { float f; unsigned int u; } c; c.f = f;
  unsigned int u = c.u;
  u += 0x7fffu + ((u >> 16) & 1u);   // round-to-nearest-even
  return (unsigned short)(u >> 16);
}

// Fused prep (lean both branches, unlike R3's register blowup):
// blocks [0, W2T_BLOCKS): 32x32 transpose tiles of [affine_w ; affine_b] -> bf16 W2t.
// blocks [W2T_BLOCKS, +1024): z + winners for 2 tokens each (identical math to R4).
__global__ __launch_bounds__(256, 4) void k_prep(
    const float* __restrict__ aw, const float* __restrict__ ab,
    const float* __restrict__ x, const float* __restrict__ proj_w,
    const float* __restrict__ router_w, const float* __restrict__ router_b,
    unsigned short* __restrict__ w2t,
    unsigned short* __restrict__ zout, unsigned long long* __restrict__ wout) {
  const int t = threadIdx.x;

  if (blockIdx.x < W2T_BLOCKS) {
    __shared__ float tile[32][33];
    const int c0 = (blockIdx.x % 132) * 32, o0 = (blockIdx.x / 132) * 32;
    const int oo = t & 31, cc = t >> 5;  // cc 0..7
#pragma unroll
    for (int p = 0; p < 4; ++p) {
      int cidx = c0 + cc + p * 8;
      float v = (cidx < AWCOLS)
                    ? aw[(size_t)cidx * OUT_DIM + o0 + oo]
                    : ab[(size_t)(cidx - AWCOLS) * OUT_DIM + o0 + oo];
      tile[cc + p * 8][oo] = v;
    }
    __syncthreads();
    if (t < 128) {
      const int ol = t >> 2, ch = t & 3;  // 32 o-rows x 4 chunks of 8 cols
      union { short8 v; unsigned short u[8]; } pk;
#pragma unroll
      for (int j = 0; j < 8; ++j) pk.u[j] = f2bf(tile[ch * 8 + j][ol]);
      *(short8*)(w2t + (size_t)(o0 + ol) * KD + c0 + ch * 8) = pk.v;
    }
    return;
  }

  // ---- zwin branch: 2 tokens/block, fp32 summation order bit-identical to R4 ----
  __shared__ __align__(16) float zbuf[2][RNK];
  __shared__ float sc[2][TGK_N];
  __shared__ int winbuf[2][TG_N];
  const int tok2 = (blockIdx.x - W2T_BLOCKS) * 2;
  const int r = t >> 3, c = t & 7;
  const float4* w4 = (const float4*)(proj_w + (size_t)r * IN_DIM);
  const float4* x0 = (const float4*)(x + (size_t)tok2 * IN_DIM);
  float a0 = 0.f, a1 = 0.f;
#pragma unroll 8
  for (int jj = 0; jj < 32; ++jj) {
    float4 wv = w4[jj * 8 + c];
    float4 xv0 = x0[jj * 8 + c];
    float4 xv1 = x0[256 + jj * 8 + c];
    a0 += xv0.x * wv.x + xv0.y * wv.y + xv0.z * wv.z + xv0.w * wv.w;
    a1 += xv1.x * wv.x + xv1.y * wv.y + xv1.z * wv.z + xv1.w * wv.w;
  }
  a0 += __shfl_xor(a0, 1); a0 += __shfl_xor(a0, 2); a0 += __shfl_xor(a0, 4);
  a1 += __shfl_xor(a1, 1); a1 += __shfl_xor(a1, 2); a1 += __shfl_xor(a1, 4);
  if (c == 0) { zbuf[0][r] = a0; zbuf[1][r] = a1; }
  __syncthreads();

  {  // thread -> (token = t>>7, cell = t&127)
    const int cell = t & 127, tk = t >> 7;
    const float4* rw = (const float4*)(router_w + (size_t)cell * RNK);
    const float4* zb = (const float4*)(&zbuf[tk][0]);
    float s = router_b[cell];
#pragma unroll
    for (int j = 0; j < 8; ++j) {
      float4 a = rw[j]; float4 b = zb[j];
      s += a.x * b.x + a.y * b.y + a.z * b.z + a.w * b.w;
    }
    sc[tk][cell] = s;
  }
  __syncthreads();

  if (t < 64) {
    const int tk = t >> 5, tg = t & 31;
    float best = sc[tk][tg * 4]; int w = 0;
#pragma unroll
    for (int k = 1; k < 4; ++k) {
      float v = sc[tk][tg * 4 + k];
      if (v < best) { best = v; w = k; }
    }
    winbuf[tk][tg] = w;
    zout[(size_t)(tok2 + tk) * RNK + tg] = f2bf(zbuf[tk][tg]);  // tg doubles as r
  }
  __syncthreads();
  if (t < 2) {
    unsigned long long w = 0ull;
    for (int g = 0; g < TG_N; ++g)
      w |= ((unsigned long long)(winbuf[t][g] & 3)) << (2 * g);
    wout[tok2 + t] = w;
  }
}

// k_gemm v4: TLP-first. Block = 32M x 16N x full-K; the 4 waves each own a
// K-quarter (kt in [0,17,34,50,66)) with NO barriers / NO LDS in the K-loop:
// per-lane B-frags straight from global (L2-resident), depth-2 register
// prefetch. Cross-wave fp32 reduce via LDS in the epilogue only.
// Grid 64x32 = 2048 blocks -> 8 blocks/CU = 32 waves/CU of latency hiding.
__global__ __launch_bounds__(256, 4) void k_gemm(
    const unsigned short* __restrict__ z, const unsigned long long* __restrict__ win,
    const unsigned short* __restrict__ Bt, float* __restrict__ out) {
  __shared__ float red[3][512];  // waves 1..3 partial accumulators
  const int bm = blockIdx.x, bn = blockIdx.y;
  const int tid = threadIdx.x;
  const int wave = tid >> 6, lane = tid & 63;
  const int l15 = lane & 15, quad = lane >> 4;

  const int m0 = bm * 32 + l15;
  const int m1 = m0 + 16;
  short8 z0 = *(const short8*)(z + (size_t)m0 * RNK + quad * 8);
  short8 z1 = *(const short8*)(z + (size_t)m1 * RNK + quad * 8);
  const unsigned long long w0 = win[m0], w1 = win[m1];

  // lane's B-frag base: row n = bn*16 + l15, chunk quad*8; k-offset = kt*64 (+32)
  const unsigned short* bp = Bt + (size_t)(bn * 16 + l15) * KD + quad * 8;

  float4v acc0 = {}, acc1 = {};

  auto compute = [&](int kt, short8 ba, short8 bb) __attribute__((always_inline)) {
    if (kt < 64) {
      const int tg = kt >> 1;
      const unsigned e0 = (unsigned)(w0 >> (2 * tg)) & 3u;
      const unsigned e1 = (unsigned)(w1 >> (2 * tg)) & 3u;
      const unsigned kk0 = (unsigned)((kt & 1) << 1), kk1 = kk0 | 1u;
      short8 zz = {};
      acc0 = __builtin_amdgcn_mfma_f32_16x16x32_bf16(e0 == kk0 ? z0 : zz, ba, acc0, 0, 0, 0);
      acc1 = __builtin_amdgcn_mfma_f32_16x16x32_bf16(e1 == kk0 ? z1 : zz, ba, acc1, 0, 0, 0);
      acc0 = __builtin_amdgcn_mfma_f32_16x16x32_bf16(e0 == kk1 ? z0 : zz, bb, acc0, 0, 0, 0);
      acc1 = __builtin_amdgcn_mfma_f32_16x16x32_bf16(e1 == kk1 ? z1 : zz, bb, acc1, 0, 0, 0);
    } else {
      // bias-indicator tiles: one-hot bf16(1.0) at winner cell (verified R2/R4)
#pragma unroll
      for (int s = 0; s < 2; ++s) {
        const int tgA = (kt - 64) * 16 + s * 8 + quad * 2;  // <= 30
        union { short8 v; unsigned long long q[2]; } fa, fb;
        fa.q[0] = 0x3F80ull << (((unsigned)(w0 >> (2 * tgA)) & 3u) * 16);
        fa.q[1] = 0x3F80ull << (((unsigned)(w0 >> (2 * (tgA + 1))) & 3u) * 16);
        fb.q[0] = 0x3F80ull << (((unsigned)(w1 >> (2 * tgA)) & 3u) * 16);
        fb.q[1] = 0x3F80ull << (((unsigned)(w1 >> (2 * (tgA + 1))) & 3u) * 16);
        short8 b = s ? bb : ba;
        acc0 = __builtin_amdgcn_mfma_f32_16x16x32_bf16(fa.v, b, acc0, 0, 0, 0);
        acc1 = __builtin_amdgcn_mfma_f32_16x16x32_bf16(fb.v, b, acc1, 0, 0, 0);
      }
    }
  };

  // wave's K-quarter: [0,17) [17,34) [34,50) [50,66)
  const int klo = (wave < 2) ? wave * 17 : 34 + (wave - 2) * 16;
  const int khi = klo + ((wave < 2) ? 17 : 16);

  short8 b0a = *(const short8*)(bp + (size_t)klo * 64);
  short8 b0b = *(const short8*)(bp + (size_t)klo * 64 + 32);
  short8 b1a = *(const short8*)(bp + (size_t)(klo + 1) * 64);
  short8 b1b = *(const short8*)(bp + (size_t)(klo + 1) * 64 + 32);

#pragma unroll 2
  for (int kt = klo; kt < khi; ++kt) {
    const int kf = (kt + 2 < khi) ? kt + 2 : khi - 1;  // clamped (valid addr) prefetch
    short8 pa = *(const short8*)(bp + (size_t)kf * 64);
    short8 pb = *(const short8*)(bp + (size_t)kf * 64 + 32);
    compute(kt, b0a, b0b);
    b0a = b1a; b0b = b1b; b1a = pa; b1b = pb;
  }

  // epilogue: cross-wave reduce. Layout red[w][j*64 + lane] -> conflict-free b32.
  if (wave > 0) {
#pragma unroll
    for (int j = 0; j < 4; ++j) {
      red[wave - 1][j * 64 + lane] = acc0[j];
      red[wave - 1][(j + 4) * 64 + lane] = acc1[j];
    }
  }
  __syncthreads();
  if (wave == 0) {
#pragma unroll
    for (int j = 0; j < 4; ++j) {
      acc0[j] += red[0][j * 64 + lane] + red[1][j * 64 + lane] + red[2][j * 64 + lane];
      acc1[j] += red[0][(j + 4) * 64 + lane] + red[1][(j + 4) * 64 + lane] + red[2][(j + 4) * 64 + lane];
    }
    const int col = bn * 16 + l15;
#pragma unroll
    for (int tm = 0; tm < 2; ++tm) {
      float4v a = tm ? acc1 : acc0;
      const int rowb = bm * 32 + tm * 16 + quad * 4;
#pragma unroll
      for (int rg = 0; rg < 4; ++rg)
        out[(size_t)(rowb + rg) * OUT_DIM + col] = a[rg] * SCALE_F;
    }
  }
}

extern "C" void kernel_launch(void* const* d_in, const int* in_sizes, int n_in,
                              void* d_out, int out_size, void* d_ws, size_t ws_size,
                              hipStream_t stream) {
  const float* x        = (const float*)d_in[0];
  const float* proj_w   = (const float*)d_in[1];
  const float* router_w = (const float*)d_in[2];
  const float* router_b = (const float*)d_in[3];
  const float* affine_w = (const float*)d_in[4];
  const float* affine_b = (const float*)d_in[5];
  float* out = (float*)d_out;

  unsigned short* zout = (unsigned short*)d_ws;                            // 128 KB
  unsigned long long* wout = (unsigned long long*)((char*)d_ws + 131072);  // 16 KB
  unsigned short* w2t = (unsigned short*)((char*)d_ws + 147456);           // 4.33 MB

  k_prep<<<W2T_BLOCKS + NTOK / 2, 256, 0, stream>>>(
      affine_w, affine_b, x, proj_w, router_w, router_b, w2t, zout, wout);
  k_gemm<<<dim3(NTOK / 32, OUT_DIM / 16), 256, 0, stream>>>(zout, wout, w2t, out);
}

// Round 6
// 108.266 us; speedup vs baseline: 1.2295x; 1.2295x over previous
//
#include <hip/hip_runtime.h>

#define NTOK 2048
#define IN_DIM 1024
#define OUT_DIM 512
#define RNK 32
#define TG_N 32
#define TGK_N 128
#define AWCOLS 4096
#define KD 4224          // 4096 affine_w cols + 128 bias-indicator cols
#define NKT 66           // KD / 64
#define SCALE_F 0.17677669529663687f

typedef __attribute__((ext_vector_type(8))) short short8;
typedef __attribute__((ext_vector_type(4))) float float4v;

__device__ __forceinline__ unsigned short f2bf(float f) {
  union { float f; unsigned int u; } c; c.f = f;
  unsigned int u = c.u;
  u += 0x7fffu + ((u >> 16) & 1u);   // round-to-nearest-even
  return (unsigned short)(u >> 16);
}

// k_w2t (verbatim R4): 32x32 transpose tiles of [affine_w ; affine_b] -> bf16 W2t.
__global__ __launch_bounds__(256) void k_w2t(
    const float* __restrict__ aw, const float* __restrict__ ab,
    unsigned short* __restrict__ w2t) {
  __shared__ float tile[32][33];
  const int c0 = blockIdx.x * 32, o0 = blockIdx.y * 32;
  const int t = threadIdx.x;
  const int oo = t & 31, cc = t >> 5;  // cc 0..7
#pragma unroll
  for (int p = 0; p < 4; ++p) {
    int cidx = c0 + cc + p * 8;
    float v = (cidx < AWCOLS)
                  ? aw[(size_t)cidx * OUT_DIM + o0 + oo]
                  : ab[(size_t)(cidx - AWCOLS) * OUT_DIM + o0 + oo];
    tile[cc + p * 8][oo] = v;
  }
  __syncthreads();
  if (t < 128) {
    const int ol = t >> 2, ch = t & 3;  // 32 o-rows x 4 chunks of 8 cols
    union { short8 v; unsigned short u[8]; } pk;
#pragma unroll
    for (int j = 0; j < 8; ++j) pk.u[j] = f2bf(tile[ch * 8 + j][ol]);
    *(short8*)(w2t + (size_t)(o0 + ol) * KD + c0 + ch * 8) = pk.v;
  }
}

// k_zwin (verbatim R4): 2 tokens/block, bit-stable fp32 scores + argmin.
__global__ __launch_bounds__(256) void k_zwin(
    const float* __restrict__ x, const float* __restrict__ proj_w,
    const float* __restrict__ router_w, const float* __restrict__ router_b,
    unsigned short* __restrict__ zout, unsigned long long* __restrict__ wout) {
  const int tok2 = blockIdx.x * 2;
  const int t = threadIdx.x;
  __shared__ __align__(16) float zbuf[2][RNK];
  __shared__ float sc[2][TGK_N];
  __shared__ int winbuf[2][TG_N];

  const int r = t >> 3, c = t & 7;
  const float4* w4 = (const float4*)(proj_w + (size_t)r * IN_DIM);
  const float4* x0 = (const float4*)(x + (size_t)tok2 * IN_DIM);
  float a0 = 0.f, a1 = 0.f;
#pragma unroll
  for (int jj = 0; jj < 32; ++jj) {
    float4 wv = w4[jj * 8 + c];
    float4 xv0 = x0[jj * 8 + c];
    float4 xv1 = x0[256 + jj * 8 + c];
    a0 += xv0.x * wv.x + xv0.y * wv.y + xv0.z * wv.z + xv0.w * wv.w;
    a1 += xv1.x * wv.x + xv1.y * wv.y + xv1.z * wv.z + xv1.w * wv.w;
  }
  a0 += __shfl_xor(a0, 1); a0 += __shfl_xor(a0, 2); a0 += __shfl_xor(a0, 4);
  a1 += __shfl_xor(a1, 1); a1 += __shfl_xor(a1, 2); a1 += __shfl_xor(a1, 4);
  if (c == 0) { zbuf[0][r] = a0; zbuf[1][r] = a1; }
  __syncthreads();

  {
    const int cell = t & 127, tk = t >> 7;
    const float4* rw = (const float4*)(router_w + (size_t)cell * RNK);
    const float4* zb = (const float4*)(&zbuf[tk][0]);
    float s = router_b[cell];
#pragma unroll
    for (int j = 0; j < 8; ++j) {
      float4 a = rw[j]; float4 b = zb[j];
      s += a.x * b.x + a.y * b.y + a.z * b.z + a.w * b.w;
    }
    sc[tk][cell] = s;
  }
  __syncthreads();

  if (t < 64) {
    const int tk = t >> 5, tg = t & 31;
    float best = sc[tk][tg * 4]; int w = 0;
#pragma unroll
    for (int k = 1; k < 4; ++k) {
      float v = sc[tk][tg * 4 + k];
      if (v < best) { best = v; w = k; }
    }
    winbuf[tk][tg] = w;
    zout[(size_t)(tok2 + tk) * RNK + tg] = f2bf(zbuf[tk][tg]);
  }
  __syncthreads();
  if (t < 2) {
    unsigned long long w = 0ull;
    for (int g = 0; g < TG_N; ++g)
      w |= ((unsigned long long)(winbuf[t][g] & 3)) << (2 * g);
    wout[tok2 + t] = w;
  }
}

// k_gemm v5: traffic-first. 128M x 32N per block -> 256 blocks (1/CU), total
// B traffic 69 MB (was 138-276). XCD-swizzled 1-D grid: blocks on XCD g read
// only bn in {2g, 2g+1} -> 540 KB B-stripe, L2-resident after first touch.
// A (z + winner bits) register-resident. B staged via the R4-verified 8-slot
// global_load_lds ring: s_waitcnt vmcnt(6) + raw s_barrier, issue-after-barrier.
// Each wave: 32M x 32N = 2x2 MFMA tiles, 8 MFMA per staged kt.
__global__ __launch_bounds__(256) void k_gemm(
    const unsigned short* __restrict__ z, const unsigned long long* __restrict__ win,
    const unsigned short* __restrict__ Bt, float* __restrict__ out) {
  __shared__ __align__(16) unsigned short Bs[8][2048];  // 8 slots x 4 KB (32n x 64k)
  // XCD-aware decode: bn_group = blk&7 pins a 540 KB B-stripe per XCD
  const int blk = blockIdx.x;
  const int g = blk & 7, rest = blk >> 3;        // rest 0..31
  const int bn = g * 2 + (rest & 1);             // 0..15
  const int bm = rest >> 1;                      // 0..15
  const int tid = threadIdx.x;
  const int wave = tid >> 6, lane = tid & 63;
  const int l15 = lane & 15, quad = lane >> 4;

  const int m0 = bm * 128 + wave * 32 + l15;
  const int m1 = m0 + 16;
  short8 z0 = *(const short8*)(z + (size_t)m0 * RNK + quad * 8);
  short8 z1 = *(const short8*)(z + (size_t)m1 * RNK + quad * 8);
  const unsigned long long w0 = win[m0], w1 = win[m1];

  // staging: thread -> (n = tid>>3, chunk = (tid&7)^(n&7)); DMA dest = lane*16
  const int sn = tid >> 3;
  const unsigned short* bsrc =
      Bt + (size_t)(bn * 32 + sn) * KD + (((tid & 7) ^ (sn & 7)) * 8);

  float4v acc00 = {}, acc01 = {}, acc10 = {}, acc11 = {};

#define ISSUE(KT)                                                                \
  __builtin_amdgcn_global_load_lds(                                              \
      (const __attribute__((address_space(1))) void*)(bsrc + (size_t)(KT) * 64), \
      (__attribute__((address_space(3))) void*)(&Bs[(KT) & 7][wave * 512]),      \
      16, 0, 0)

  auto compute = [&](int kt) __attribute__((always_inline)) {
    const unsigned short* sb = &Bs[kt & 7][0];
    const int fn0 = l15, fn1 = 16 + l15;  // the two n-tiles' B rows
    if (kt < 64) {
      const int tg = kt >> 1;
      const unsigned e0 = (unsigned)(w0 >> (2 * tg)) & 3u;
      const unsigned e1 = (unsigned)(w1 >> (2 * tg)) & 3u;
#pragma unroll
      for (int s = 0; s < 2; ++s) {
        const unsigned kk = (unsigned)(((kt & 1) << 1) | s);
        short8 zz = {};
        short8 a0 = (e0 == kk) ? z0 : zz;
        short8 a1 = (e1 == kk) ? z1 : zz;
        short8 b0 = *(const short8*)(sb + fn0 * 64 + (((s * 4 + quad) ^ (fn0 & 7)) * 8));
        short8 b1 = *(const short8*)(sb + fn1 * 64 + (((s * 4 + quad) ^ (fn1 & 7)) * 8));
        acc00 = __builtin_amdgcn_mfma_f32_16x16x32_bf16(a0, b0, acc00, 0, 0, 0);
        acc01 = __builtin_amdgcn_mfma_f32_16x16x32_bf16(a0, b1, acc01, 0, 0, 0);
        acc10 = __builtin_amdgcn_mfma_f32_16x16x32_bf16(a1, b0, acc10, 0, 0, 0);
        acc11 = __builtin_amdgcn_mfma_f32_16x16x32_bf16(a1, b1, acc11, 0, 0, 0);
      }
    } else {
      // bias-indicator tiles: one-hot bf16(1.0) at winner cell (verified R2-R5)
#pragma unroll
      for (int s = 0; s < 2; ++s) {
        const int tgA = (kt - 64) * 16 + s * 8 + quad * 2;  // <= 30
        union { short8 v; unsigned long long q[2]; } fa, fb;
        fa.q[0] = 0x3F80ull << (((unsigned)(w0 >> (2 * tgA)) & 3u) * 16);
        fa.q[1] = 0x3F80ull << (((unsigned)(w0 >> (2 * (tgA + 1))) & 3u) * 16);
        fb.q[0] = 0x3F80ull << (((unsigned)(w1 >> (2 * tgA)) & 3u) * 16);
        fb.q[1] = 0x3F80ull << (((unsigned)(w1 >> (2 * (tgA + 1))) & 3u) * 16);
        short8 b0 = *(const short8*)(sb + fn0 * 64 + (((s * 4 + quad) ^ (fn0 & 7)) * 8));
        short8 b1 = *(const short8*)(sb + fn1 * 64 + (((s * 4 + quad) ^ (fn1 & 7)) * 8));
        acc00 = __builtin_amdgcn_mfma_f32_16x16x32_bf16(fa.v, b0, acc00, 0, 0, 0);
        acc01 = __builtin_amdgcn_mfma_f32_16x16x32_bf16(fa.v, b1, acc01, 0, 0, 0);
        acc10 = __builtin_amdgcn_mfma_f32_16x16x32_bf16(fb.v, b0, acc10, 0, 0, 0);
        acc11 = __builtin_amdgcn_mfma_f32_16x16x32_bf16(fb.v, b1, acc11, 0, 0, 0);
      }
    }
  };

  ISSUE(0); ISSUE(1); ISSUE(2); ISSUE(3); ISSUE(4); ISSUE(5); ISSUE(6);

  for (int kt = 0; kt < 60; ++kt) {
    asm volatile("s_waitcnt vmcnt(6)" ::: "memory");  // slot kt landed; 6 in flight
    asm volatile("s_barrier" ::: "memory");           // everyone past compute(kt-1)
    if (kt <= 58) ISSUE(kt + 7);                      // overwrites slot of kt-1: safe
    compute(kt);
  }
  asm volatile("s_waitcnt vmcnt(5)" ::: "memory"); asm volatile("s_barrier" ::: "memory"); compute(60);
  asm volatile("s_waitcnt vmcnt(4)" ::: "memory"); asm volatile("s_barrier" ::: "memory"); compute(61);
  asm volatile("s_waitcnt vmcnt(3)" ::: "memory"); asm volatile("s_barrier" ::: "memory"); compute(62);
  asm volatile("s_waitcnt vmcnt(2)" ::: "memory"); asm volatile("s_barrier" ::: "memory"); compute(63);
  asm volatile("s_waitcnt vmcnt(1)" ::: "memory"); asm volatile("s_barrier" ::: "memory"); compute(64);
  asm volatile("s_waitcnt vmcnt(0)" ::: "memory"); asm volatile("s_barrier" ::: "memory"); compute(65);
#undef ISSUE

  // epilogue: C/D layout col = lane&15, row = quad*4 + reg; waves own disjoint M
#pragma unroll
  for (int tm = 0; tm < 2; ++tm) {
#pragma unroll
    for (int tn = 0; tn < 2; ++tn) {
      float4v a = tm ? (tn ? acc11 : acc10) : (tn ? acc01 : acc00);
      const int col = bn * 32 + tn * 16 + l15;
      const int rowb = bm * 128 + wave * 32 + tm * 16 + quad * 4;
#pragma unroll
      for (int rg = 0; rg < 4; ++rg)
        out[(size_t)(rowb + rg) * OUT_DIM + col] = a[rg] * SCALE_F;
    }
  }
}

extern "C" void kernel_launch(void* const* d_in, const int* in_sizes, int n_in,
                              void* d_out, int out_size, void* d_ws, size_t ws_size,
                              hipStream_t stream) {
  const float* x        = (const float*)d_in[0];
  const float* proj_w   = (const float*)d_in[1];
  const float* router_w = (const float*)d_in[2];
  const float* router_b = (const float*)d_in[3];
  const float* affine_w = (const float*)d_in[4];
  const float* affine_b = (const float*)d_in[5];
  float* out = (float*)d_out;

  unsigned short* zout = (unsigned short*)d_ws;                            // 128 KB
  unsigned long long* wout = (unsigned long long*)((char*)d_ws + 131072);  // 16 KB
  unsigned short* w2t = (unsigned short*)((char*)d_ws + 147456);           // 4.33 MB

  k_w2t<<<dim3(KD / 32, OUT_DIM / 32), 256, 0, stream>>>(affine_w, affine_b, w2t);
  k_zwin<<<NTOK / 2, 256, 0, stream>>>(x, proj_w, router_w, router_b, zout, wout);
  k_gemm<<<256, 256, 0, stream>>>(zout, wout, w2t, out);
}